// Round 1
// baseline (227913.965 us; speedup 1.0000x reference)
//
#include <hip/hip_runtime.h>
#include <math.h>

#define NWG  256
#define NTHR 256

// LDS float offsets
#define O_W2  0        // [16][1024]
#define O_W1  16384    // [16][512]
#define O_U   24576    // union: hstage [8][1024]  /  red [128][68]  (8704 floats)
#define O_WX  33280    // [16][2]
#define O_B1  33312    // [16]
#define O_B2  33328    // [16]
#define O_WO  33344    // [4]
#define O_XS  33348    // [8][2]
#define O_GAT 33364    // [128]
#define O_C1  33492    // [32]
#define O_C2  33524    // [32]
#define O_HN  33556    // [32]
#define LDS_FLOATS 33600

__global__ void ws_init_kernel(unsigned* flags) {
    for (int i = threadIdx.x; i < NWG * 16; i += blockDim.x) flags[i] = 0u;
}

__device__ __forceinline__ float sigm(float x) { return 1.0f / (1.0f + __expf(-x)); }
__device__ __forceinline__ float tanh_fast(float x) { return 2.0f / (1.0f + __expf(-2.0f * x)) - 1.0f; }

__device__ __forceinline__ void gbar(unsigned* flags, int wg, int tid, unsigned ph) {
    __syncthreads();
    if (tid == 0) {
        __threadfence();   // release: drain + L2 writeback (agent scope)
        __hip_atomic_store(&flags[wg * 16], ph, __ATOMIC_RELEASE, __HIP_MEMORY_SCOPE_AGENT);
    }
    unsigned v = __hip_atomic_load(&flags[tid * 16], __ATOMIC_RELAXED, __HIP_MEMORY_SCOPE_AGENT);
    while (v < ph) {
        __builtin_amdgcn_s_sleep(2);
        v = __hip_atomic_load(&flags[tid * 16], __ATOMIC_RELAXED, __HIP_MEMORY_SCOPE_AGENT);
    }
    __syncthreads();
    if (tid == 0) __threadfence();   // acquire: invalidate L1/L2 so h reads see other XCDs
    __syncthreads();
}

__global__ __launch_bounds__(NTHR, 1) void lstm_kernel(
    const float* __restrict__ xin,  const float* __restrict__ Wih1,
    const float* __restrict__ Whh1, const float* __restrict__ bih1,
    const float* __restrict__ bhh1, const float* __restrict__ Wih2,
    const float* __restrict__ Whh2, const float* __restrict__ bih2,
    const float* __restrict__ bhh2, const float* __restrict__ Wout,
    const float* __restrict__ bout, float* __restrict__ out,
    unsigned* __restrict__ flags, float* __restrict__ h1g,
    float* __restrict__ h2g, float* __restrict__ outred, int T)
{
    __shared__ float lds[LDS_FLOATS];
    const int tid = threadIdx.x;
    const int wg  = blockIdx.x;
    const int bh  = wg & 1;         // batch half: batches bh*8 .. bh*8+7
    const int jg  = wg >> 1;        // hidden-j group
    const int j0  = jg * 4;

    // ---- one-time: load weight slice into LDS ----
    for (int idx = tid; idx < 2048; idx += NTHR) {          // W1 = W_hh1 rows
        int r = idx >> 7, c4 = idx & 127;
        int grow = (r >> 2) * 512 + j0 + (r & 3);           // r = q*4+jj -> global row q*512+j
        *(float4*)&lds[O_W1 + r * 512 + c4 * 4] = *(const float4*)&Whh1[grow * 512 + c4 * 4];
    }
    for (int idx = tid; idx < 4096; idx += NTHR) {          // W2 = [W_ih2 | W_hh2] concat over K
        int r = idx >> 8, c4 = idx & 255;
        int grow = (r >> 2) * 512 + j0 + (r & 3);
        int k = c4 * 4;
        const float* src = (k < 512) ? &Wih2[grow * 512 + k] : &Whh2[grow * 512 + (k - 512)];
        *(float4*)&lds[O_W2 + r * 1024 + k] = *(const float4*)src;
    }
    if (tid < 32) {
        int r = tid >> 1, grow = (r >> 2) * 512 + j0 + (r & 3);
        lds[O_WX + tid] = Wih1[grow * 2 + (tid & 1)];
    }
    if (tid < 16) {
        int grow = (tid >> 2) * 512 + j0 + (tid & 3);
        lds[O_B1 + tid] = bih1[grow] + bhh1[grow];
        lds[O_B2 + tid] = bih2[grow] + bhh2[grow];
    }
    if (tid < 4) lds[O_WO + tid] = Wout[j0 + tid];
    if (tid < 32) { lds[O_C1 + tid] = 0.0f; lds[O_C2 + tid] = 0.0f; }
    const float bo = bout[0];
    __syncthreads();

    const int wv = tid >> 6;        // wave id -> row group (4 rows)
    const int ks = tid & 63;        // K-split lane
    unsigned ph = 0;

    for (int t = 0; t < T; ++t) {
        const int p = t & 1, pq = p ^ 1;

        // ================= phase A : layer 1 =================
        // out-duty for step t-1 (reads outred[pq], written before last barrier)
        if (wg < 16 && t > 0 && tid < 64) {
            const float* row = outred + pq * 2048 + wg * 128;
            float s = row[tid * 2] + row[tid * 2 + 1];
            #pragma unroll
            for (int off = 32; off >= 1; off >>= 1) s += __shfl_xor(s, off);
            if (tid == 0) out[wg * T + (t - 1)] = s + bo;
        }
        // stage h1_prev -> U[b][0..511] (row stride 1024)
        if (t == 0) {
            for (int idx = tid; idx < 1024; idx += NTHR) {
                int b = idx >> 7, c4 = idx & 127;
                *(float4*)&lds[O_U + b * 1024 + c4 * 4] = make_float4(0.f, 0.f, 0.f, 0.f);
            }
        } else {
            const float* src = h1g + pq * 8192;
            for (int idx = tid; idx < 1024; idx += NTHR) {
                int b = idx >> 7, c4 = idx & 127;
                *(float4*)&lds[O_U + b * 1024 + c4 * 4] =
                    *(const float4*)&src[(bh * 8 + b) * 512 + c4 * 4];
            }
        }
        if (tid < 16) {
            int b = tid >> 1, cm = tid & 1;
            lds[O_XS + tid] = xin[((bh * 8 + b) * (long)T + t) * 2 + cm];
        }
        __syncthreads();

        {   // gates: rows (4*wv..4*wv+3) x 8 batches, K=512 split over 64 lanes
            float acc[4][8];
            #pragma unroll
            for (int r = 0; r < 4; ++r)
                #pragma unroll
                for (int b = 0; b < 8; ++b) acc[r][b] = 0.0f;
            const float* Wb = &lds[O_W1 + wv * 4 * 512];
            #pragma unroll
            for (int c = 0; c < 2; ++c) {
                int k = ks * 4 + c * 256;
                float4 w0 = *(const float4*)&Wb[0 * 512 + k];
                float4 w1 = *(const float4*)&Wb[1 * 512 + k];
                float4 w2 = *(const float4*)&Wb[2 * 512 + k];
                float4 w3 = *(const float4*)&Wb[3 * 512 + k];
                #pragma unroll
                for (int b = 0; b < 8; ++b) {
                    float4 h = *(const float4*)&lds[O_U + b * 1024 + k];
                    acc[0][b] = fmaf(w0.x,h.x,fmaf(w0.y,h.y,fmaf(w0.z,h.z,fmaf(w0.w,h.w,acc[0][b]))));
                    acc[1][b] = fmaf(w1.x,h.x,fmaf(w1.y,h.y,fmaf(w1.z,h.z,fmaf(w1.w,h.w,acc[1][b]))));
                    acc[2][b] = fmaf(w2.x,h.x,fmaf(w2.y,h.y,fmaf(w2.z,h.z,fmaf(w2.w,h.w,acc[2][b]))));
                    acc[3][b] = fmaf(w3.x,h.x,fmaf(w3.y,h.y,fmaf(w3.z,h.z,fmaf(w3.w,h.w,acc[3][b]))));
                }
            }
            __syncthreads();            // done reading hstage; U becomes red[]
            #pragma unroll
            for (int r = 0; r < 4; ++r)
                #pragma unroll
                for (int b = 0; b < 8; ++b)
                    lds[O_U + ((wv * 4 + r) * 8 + b) * 68 + ks] = acc[r][b];
        }
        __syncthreads();
        {   // K-reduce + bias + x-part
            int o = tid >> 1, hf = tid & 1;
            const float* rr = &lds[O_U + o * 68 + hf * 32];
            float s = 0.0f;
            #pragma unroll
            for (int c = 0; c < 8; ++c) { float4 v = *(const float4*)&rr[c * 4]; s += v.x + v.y + v.z + v.w; }
            s += __shfl_xor(s, 1);
            if (hf == 0) {
                int r = o >> 3, b = o & 7;
                lds[O_GAT + o] = s + lds[O_B1 + r]
                               + lds[O_WX + r * 2]     * lds[O_XS + b * 2]
                               + lds[O_WX + r * 2 + 1] * lds[O_XS + b * 2 + 1];
            }
        }
        __syncthreads();
        if (tid < 32) {     // activations + cell update + publish h1
            int jj = tid >> 3, b = tid & 7;
            float gi = sigm(lds[O_GAT + (0 * 4 + jj) * 8 + b]);
            float gf = sigm(lds[O_GAT + (1 * 4 + jj) * 8 + b]);
            float gg = tanh_fast(lds[O_GAT + (2 * 4 + jj) * 8 + b]);
            float go = sigm(lds[O_GAT + (3 * 4 + jj) * 8 + b]);
            float c  = gf * lds[O_C1 + tid] + gi * gg;
            lds[O_C1 + tid] = c;
            h1g[p * 8192 + (bh * 8 + b) * 512 + j0 + jj] = go * tanh_fast(c);
        }
        gbar(flags, wg, tid, ++ph);

        // ================= phase B : layer 2 =================
        for (int idx = tid; idx < 2048; idx += NTHR) {   // stage [h1(t) | h2(t-1)]
            int b = idx >> 8, c4 = idx & 255;
            int k = c4 * 4;
            float4 v;
            if (k < 512)       v = *(const float4*)&h1g[p * 8192 + (bh * 8 + b) * 512 + k];
            else if (t == 0)   v = make_float4(0.f, 0.f, 0.f, 0.f);
            else               v = *(const float4*)&h2g[pq * 8192 + (bh * 8 + b) * 512 + (k - 512)];
            *(float4*)&lds[O_U + b * 1024 + k] = v;
        }
        __syncthreads();
        {
            float acc[4][8];
            #pragma unroll
            for (int r = 0; r < 4; ++r)
                #pragma unroll
                for (int b = 0; b < 8; ++b) acc[r][b] = 0.0f;
            const float* Wb = &lds[O_W2 + wv * 4 * 1024];
            #pragma unroll
            for (int c = 0; c < 4; ++c) {
                int k = ks * 4 + c * 256;
                float4 w0 = *(const float4*)&Wb[0 * 1024 + k];
                float4 w1 = *(const float4*)&Wb[1 * 1024 + k];
                float4 w2 = *(const float4*)&Wb[2 * 1024 + k];
                float4 w3 = *(const float4*)&Wb[3 * 1024 + k];
                #pragma unroll
                for (int b = 0; b < 8; ++b) {
                    float4 h = *(const float4*)&lds[O_U + b * 1024 + k];
                    acc[0][b] = fmaf(w0.x,h.x,fmaf(w0.y,h.y,fmaf(w0.z,h.z,fmaf(w0.w,h.w,acc[0][b]))));
                    acc[1][b] = fmaf(w1.x,h.x,fmaf(w1.y,h.y,fmaf(w1.z,h.z,fmaf(w1.w,h.w,acc[1][b]))));
                    acc[2][b] = fmaf(w2.x,h.x,fmaf(w2.y,h.y,fmaf(w2.z,h.z,fmaf(w2.w,h.w,acc[2][b]))));
                    acc[3][b] = fmaf(w3.x,h.x,fmaf(w3.y,h.y,fmaf(w3.z,h.z,fmaf(w3.w,h.w,acc[3][b]))));
                }
            }
            __syncthreads();
            #pragma unroll
            for (int r = 0; r < 4; ++r)
                #pragma unroll
                for (int b = 0; b < 8; ++b)
                    lds[O_U + ((wv * 4 + r) * 8 + b) * 68 + ks] = acc[r][b];
        }
        __syncthreads();
        {
            int o = tid >> 1, hf = tid & 1;
            const float* rr = &lds[O_U + o * 68 + hf * 32];
            float s = 0.0f;
            #pragma unroll
            for (int c = 0; c < 8; ++c) { float4 v = *(const float4*)&rr[c * 4]; s += v.x + v.y + v.z + v.w; }
            s += __shfl_xor(s, 1);
            if (hf == 0) {
                int r = o >> 3;
                lds[O_GAT + o] = s + lds[O_B2 + r];
            }
        }
        __syncthreads();
        if (tid < 32) {
            int jj = tid >> 3, b = tid & 7;
            float gi = sigm(lds[O_GAT + (0 * 4 + jj) * 8 + b]);
            float gf = sigm(lds[O_GAT + (1 * 4 + jj) * 8 + b]);
            float gg = tanh_fast(lds[O_GAT + (2 * 4 + jj) * 8 + b]);
            float go = sigm(lds[O_GAT + (3 * 4 + jj) * 8 + b]);
            float c  = gf * lds[O_C2 + tid] + gi * gg;
            lds[O_C2 + tid] = c;
            float h = go * tanh_fast(c);
            h2g[p * 8192 + (bh * 8 + b) * 512 + j0 + jj] = h;
            lds[O_HN + tid] = lds[O_WO + jj] * h;      // product for W_out dot
        }
        __syncthreads();
        if (tid < 8) {      // per-batch partial of W_out dot for this j-group
            float pr = lds[O_HN + tid] + lds[O_HN + 8 + tid] + lds[O_HN + 16 + tid] + lds[O_HN + 24 + tid];
            outred[p * 2048 + (bh * 8 + tid) * 128 + jg] = pr;
        }
        gbar(flags, wg, tid, ++ph);
    }

    // tail: output for t = T-1
    if (wg < 16 && tid < 64) {
        const float* row = outred + ((T - 1) & 1) * 2048 + wg * 128;
        float s = row[tid * 2] + row[tid * 2 + 1];
        #pragma unroll
        for (int off = 32; off >= 1; off >>= 1) s += __shfl_xor(s, off);
        if (tid == 0) out[wg * T + (T - 1)] = s + bo;
    }
}

extern "C" void kernel_launch(void* const* d_in, const int* in_sizes, int n_in,
                              void* d_out, int out_size, void* d_ws, size_t ws_size,
                              hipStream_t stream) {
    const float* xin  = (const float*)d_in[0];
    const float* Wih1 = (const float*)d_in[1];
    const float* Whh1 = (const float*)d_in[2];
    const float* bih1 = (const float*)d_in[3];
    const float* bhh1 = (const float*)d_in[4];
    const float* Wih2 = (const float*)d_in[5];
    const float* Whh2 = (const float*)d_in[6];
    const float* bih2 = (const float*)d_in[7];
    const float* bhh2 = (const float*)d_in[8];
    const float* Wout = (const float*)d_in[9];
    const float* bout = (const float*)d_in[10];
    float* outp = (float*)d_out;
    int T = in_sizes[0] / 32;           // input is [16][T][2]

    unsigned* flags = (unsigned*)d_ws;                  // 256 * 16 uints (64B-padded flags)
    float* h1g    = (float*)d_ws + 4096;                // [2][16][512]
    float* h2g    = h1g + 16384;                        // [2][16][512]
    float* outredp= h2g + 16384;                        // [2][16][128]

    hipLaunchKernelGGL(ws_init_kernel, dim3(1), dim3(256), 0, stream, flags);

    void* args[] = { &xin, &Wih1, &Whh1, &bih1, &bhh1, &Wih2, &Whh2, &bih2, &bhh2,
                     &Wout, &bout, &outp, &flags, &h1g, &h2g, &outredp, &T };
    hipLaunchCooperativeKernel((void*)lstm_kernel, dim3(NWG), dim3(NTHR), args, 0, stream);
}

// Round 5
// 223660.571 us; speedup vs baseline: 1.0190x; 1.0190x over previous
//
#include <hip/hip_runtime.h>
#include <math.h>

#define NWG  256
#define NTHR 256

// LDS float offsets
#define O_W2  0        // [16][1024]
#define O_W1  16384    // [16][512]
#define O_U   24576    // union: hstage [8][1024]  /  red [128][68]  (8704 floats)
#define O_WX  33280    // [16][2]
#define O_B1  33312    // [16]
#define O_B2  33328    // [16]
#define O_WO  33344    // [4]
#define O_XS  33348    // [8][2]
#define O_GAT 33364    // [128]
#define O_C1  33492    // [32]
#define O_C2  33524    // [32]
#define O_HN  33556    // [32]
#define LDS_FLOATS 33600

__global__ void ws_init_kernel(unsigned* flags) {
    for (int i = threadIdx.x; i < NWG * 16; i += blockDim.x) flags[i] = 0u;
}

__device__ __forceinline__ float sigm(float x) { return 1.0f / (1.0f + __expf(-x)); }
__device__ __forceinline__ float tanh_fast(float x) { return 2.0f / (1.0f + __expf(-2.0f * x)) - 1.0f; }

// Round-1 fence structure (empirically sound over 6574 steps), new poll:
// wave 0 polls 256 PACKED u32 flags (16 cache lines) instead of 65536
// threads polling 256 scattered lines.
__device__ __forceinline__ void gbar(unsigned* flags, int wg, int tid, unsigned ph) {
    __syncthreads();
    if (tid == 0) {
        __threadfence();   // release: drain wave-0 stores + L2 writeback (agent scope)
        __hip_atomic_store(&flags[wg], ph, __ATOMIC_RELAXED, __HIP_MEMORY_SCOPE_AGENT);
    }
    if (tid < 64) {
        const unsigned long long* f64 = (const unsigned long long*)flags;
        bool done;
        do {
            unsigned long long v0 = __hip_atomic_load(&f64[tid],      __ATOMIC_RELAXED, __HIP_MEMORY_SCOPE_AGENT);
            unsigned long long v1 = __hip_atomic_load(&f64[tid + 64], __ATOMIC_RELAXED, __HIP_MEMORY_SCOPE_AGENT);
            done = ((unsigned)v0 >= ph) && ((unsigned)(v0 >> 32) >= ph) &&
                   ((unsigned)v1 >= ph) && ((unsigned)(v1 >> 32) >= ph);
            if (!__all(done)) __builtin_amdgcn_s_sleep(1);
        } while (!__all(done));
    }
    __syncthreads();
    if (tid == 0) __threadfence();   // acquire: invalidate caches so staged reads are fresh
    __syncthreads();
}

__global__ __launch_bounds__(NTHR, 1) void lstm_kernel(
    const float* __restrict__ xin,  const float* __restrict__ Wih1,
    const float* __restrict__ Whh1, const float* __restrict__ bih1,
    const float* __restrict__ bhh1, const float* __restrict__ Wih2,
    const float* __restrict__ Whh2, const float* __restrict__ bih2,
    const float* __restrict__ bhh2, const float* __restrict__ Wout,
    const float* __restrict__ bout, float* __restrict__ out,
    unsigned* __restrict__ flags, float* __restrict__ h1g,
    float* __restrict__ h2g, float* __restrict__ outred, int T)
{
    __shared__ float lds[LDS_FLOATS];
    const int tid = threadIdx.x;
    const int wg  = blockIdx.x;
    const int bh  = wg & 1;         // batch half: batches bh*8 .. bh*8+7
    const int jg  = wg >> 1;        // hidden-j group
    const int j0  = jg * 4;

    // ---- one-time: load weight slice into LDS ----
    for (int idx = tid; idx < 2048; idx += NTHR) {          // W1 = W_hh1 rows
        int r = idx >> 7, c4 = idx & 127;
        int grow = (r >> 2) * 512 + j0 + (r & 3);           // r = q*4+jj -> global row q*512+j
        *(float4*)&lds[O_W1 + r * 512 + c4 * 4] = *(const float4*)&Whh1[grow * 512 + c4 * 4];
    }
    for (int idx = tid; idx < 4096; idx += NTHR) {          // W2 = [W_ih2 | W_hh2] concat over K
        int r = idx >> 8, c4 = idx & 255;
        int grow = (r >> 2) * 512 + j0 + (r & 3);
        int k = c4 * 4;
        const float* src = (k < 512) ? &Wih2[grow * 512 + k] : &Whh2[grow * 512 + (k - 512)];
        *(float4*)&lds[O_W2 + r * 1024 + k] = *(const float4*)src;
    }
    if (tid < 32) {
        int r = tid >> 1, grow = (r >> 2) * 512 + j0 + (r & 3);
        lds[O_WX + tid] = Wih1[grow * 2 + (tid & 1)];
    }
    if (tid < 16) {
        int grow = (tid >> 2) * 512 + j0 + (tid & 3);
        lds[O_B1 + tid] = bih1[grow] + bhh1[grow];
        lds[O_B2 + tid] = bih2[grow] + bhh2[grow];
    }
    if (tid < 4) lds[O_WO + tid] = Wout[j0 + tid];
    if (tid < 32) { lds[O_C1 + tid] = 0.0f; lds[O_C2 + tid] = 0.0f; }
    const float bo = bout[0];
    __syncthreads();

    const int wv = tid >> 6;        // wave id -> row group (4 rows)
    const int ks = tid & 63;        // K-split lane
    unsigned ph = 0;

    for (int t = 0; t < T; ++t) {
        const int p = t & 1, pq = p ^ 1;

        // ================= phase A : layer 1 =================
        // out-duty for step t-1 (reads outred[pq], written before last barrier)
        if (wg < 16 && t > 0 && tid < 64) {
            const float* row = outred + pq * 2048 + wg * 128;
            float s = row[tid * 2] + row[tid * 2 + 1];
            #pragma unroll
            for (int off = 32; off >= 1; off >>= 1) s += __shfl_xor(s, off);
            if (tid == 0) out[wg * T + (t - 1)] = s + bo;
        }
        // stage h1_prev -> U[b][0..511] (row stride 1024)
        if (t == 0) {
            for (int idx = tid; idx < 1024; idx += NTHR) {
                int b = idx >> 7, c4 = idx & 127;
                *(float4*)&lds[O_U + b * 1024 + c4 * 4] = make_float4(0.f, 0.f, 0.f, 0.f);
            }
        } else {
            const float* src = h1g + pq * 8192;
            for (int idx = tid; idx < 1024; idx += NTHR) {
                int b = idx >> 7, c4 = idx & 127;
                *(float4*)&lds[O_U + b * 1024 + c4 * 4] =
                    *(const float4*)&src[(bh * 8 + b) * 512 + c4 * 4];
            }
        }
        if (tid < 16) {
            int b = tid >> 1, cm = tid & 1;
            lds[O_XS + tid] = xin[((bh * 8 + b) * (long)T + t) * 2 + cm];
        }
        __syncthreads();

        {   // gates: rows (4*wv..4*wv+3) x 8 batches, K=512 split over 64 lanes
            float acc[4][8];
            #pragma unroll
            for (int r = 0; r < 4; ++r)
                #pragma unroll
                for (int b = 0; b < 8; ++b) acc[r][b] = 0.0f;
            const float* Wb = &lds[O_W1 + wv * 4 * 512];
            #pragma unroll
            for (int c = 0; c < 2; ++c) {
                int k = ks * 4 + c * 256;
                float4 w0 = *(const float4*)&Wb[0 * 512 + k];
                float4 w1 = *(const float4*)&Wb[1 * 512 + k];
                float4 w2 = *(const float4*)&Wb[2 * 512 + k];
                float4 w3 = *(const float4*)&Wb[3 * 512 + k];
                #pragma unroll
                for (int b = 0; b < 8; ++b) {
                    float4 h = *(const float4*)&lds[O_U + b * 1024 + k];
                    acc[0][b] = fmaf(w0.x,h.x,fmaf(w0.y,h.y,fmaf(w0.z,h.z,fmaf(w0.w,h.w,acc[0][b]))));
                    acc[1][b] = fmaf(w1.x,h.x,fmaf(w1.y,h.y,fmaf(w1.z,h.z,fmaf(w1.w,h.w,acc[1][b]))));
                    acc[2][b] = fmaf(w2.x,h.x,fmaf(w2.y,h.y,fmaf(w2.z,h.z,fmaf(w2.w,h.w,acc[2][b]))));
                    acc[3][b] = fmaf(w3.x,h.x,fmaf(w3.y,h.y,fmaf(w3.z,h.z,fmaf(w3.w,h.w,acc[3][b]))));
                }
            }
            __syncthreads();            // done reading hstage; U becomes red[]
            #pragma unroll
            for (int r = 0; r < 4; ++r)
                #pragma unroll
                for (int b = 0; b < 8; ++b)
                    lds[O_U + ((wv * 4 + r) * 8 + b) * 68 + ks] = acc[r][b];
        }
        __syncthreads();
        {   // K-reduce + bias + x-part
            int o = tid >> 1, hf = tid & 1;
            const float* rr = &lds[O_U + o * 68 + hf * 32];
            float s = 0.0f;
            #pragma unroll
            for (int c = 0; c < 8; ++c) { float4 v = *(const float4*)&rr[c * 4]; s += v.x + v.y + v.z + v.w; }
            s += __shfl_xor(s, 1);
            if (hf == 0) {
                int r = o >> 3, b = o & 7;
                lds[O_GAT + o] = s + lds[O_B1 + r]
                               + lds[O_WX + r * 2]     * lds[O_XS + b * 2]
                               + lds[O_WX + r * 2 + 1] * lds[O_XS + b * 2 + 1];
            }
        }
        __syncthreads();
        if (tid < 32) {     // activations + cell update + publish h1
            int jj = tid >> 3, b = tid & 7;
            float gi = sigm(lds[O_GAT + (0 * 4 + jj) * 8 + b]);
            float gf = sigm(lds[O_GAT + (1 * 4 + jj) * 8 + b]);
            float gg = tanh_fast(lds[O_GAT + (2 * 4 + jj) * 8 + b]);
            float go = sigm(lds[O_GAT + (3 * 4 + jj) * 8 + b]);
            float c  = gf * lds[O_C1 + tid] + gi * gg;
            lds[O_C1 + tid] = c;
            h1g[p * 8192 + (bh * 8 + b) * 512 + j0 + jj] = go * tanh_fast(c);
        }
        gbar(flags, wg, tid, ++ph);

        // ================= phase B : layer 2 =================
        for (int idx = tid; idx < 2048; idx += NTHR) {   // stage [h1(t) | h2(t-1)]
            int b = idx >> 8, c4 = idx & 255;
            int k = c4 * 4;
            float4 v;
            if (k < 512)       v = *(const float4*)&h1g[p * 8192 + (bh * 8 + b) * 512 + k];
            else if (t == 0)   v = make_float4(0.f, 0.f, 0.f, 0.f);
            else               v = *(const float4*)&h2g[pq * 8192 + (bh * 8 + b) * 512 + (k - 512)];
            *(float4*)&lds[O_U + b * 1024 + k] = v;
        }
        __syncthreads();
        {
            float acc[4][8];
            #pragma unroll
            for (int r = 0; r < 4; ++r)
                #pragma unroll
                for (int b = 0; b < 8; ++b) acc[r][b] = 0.0f;
            const float* Wb = &lds[O_W2 + wv * 4 * 1024];
            #pragma unroll
            for (int c = 0; c < 4; ++c) {
                int k = ks * 4 + c * 256;
                float4 w0 = *(const float4*)&Wb[0 * 1024 + k];
                float4 w1 = *(const float4*)&Wb[1 * 1024 + k];
                float4 w2 = *(const float4*)&Wb[2 * 1024 + k];
                float4 w3 = *(const float4*)&Wb[3 * 1024 + k];
                #pragma unroll
                for (int b = 0; b < 8; ++b) {
                    float4 h = *(const float4*)&lds[O_U + b * 1024 + k];
                    acc[0][b] = fmaf(w0.x,h.x,fmaf(w0.y,h.y,fmaf(w0.z,h.z,fmaf(w0.w,h.w,acc[0][b]))));
                    acc[1][b] = fmaf(w1.x,h.x,fmaf(w1.y,h.y,fmaf(w1.z,h.z,fmaf(w1.w,h.w,acc[1][b]))));
                    acc[2][b] = fmaf(w2.x,h.x,fmaf(w2.y,h.y,fmaf(w2.z,h.z,fmaf(w2.w,h.w,acc[2][b]))));
                    acc[3][b] = fmaf(w3.x,h.x,fmaf(w3.y,h.y,fmaf(w3.z,h.z,fmaf(w3.w,h.w,acc[3][b]))));
                }
            }
            __syncthreads();
            #pragma unroll
            for (int r = 0; r < 4; ++r)
                #pragma unroll
                for (int b = 0; b < 8; ++b)
                    lds[O_U + ((wv * 4 + r) * 8 + b) * 68 + ks] = acc[r][b];
        }
        __syncthreads();
        {
            int o = tid >> 1, hf = tid & 1;
            const float* rr = &lds[O_U + o * 68 + hf * 32];
            float s = 0.0f;
            #pragma unroll
            for (int c = 0; c < 8; ++c) { float4 v = *(const float4*)&rr[c * 4]; s += v.x + v.y + v.z + v.w; }
            s += __shfl_xor(s, 1);
            if (hf == 0) {
                int r = o >> 3;
                lds[O_GAT + o] = s + lds[O_B2 + r];
            }
        }
        __syncthreads();
        if (tid < 32) {
            int jj = tid >> 3, b = tid & 7;
            float gi = sigm(lds[O_GAT + (0 * 4 + jj) * 8 + b]);
            float gf = sigm(lds[O_GAT + (1 * 4 + jj) * 8 + b]);
            float gg = tanh_fast(lds[O_GAT + (2 * 4 + jj) * 8 + b]);
            float go = sigm(lds[O_GAT + (3 * 4 + jj) * 8 + b]);
            float c  = gf * lds[O_C2 + tid] + gi * gg;
            lds[O_C2 + tid] = c;
            float h = go * tanh_fast(c);
            h2g[p * 8192 + (bh * 8 + b) * 512 + j0 + jj] = h;
            lds[O_HN + tid] = lds[O_WO + jj] * h;      // product for W_out dot
        }
        __syncthreads();
        if (tid < 8) {      // per-batch partial of W_out dot for this j-group
            float pr = lds[O_HN + tid] + lds[O_HN + 8 + tid] + lds[O_HN + 16 + tid] + lds[O_HN + 24 + tid];
            outred[p * 2048 + (bh * 8 + tid) * 128 + jg] = pr;
        }
        gbar(flags, wg, tid, ++ph);
    }

    // tail: output for t = T-1
    if (wg < 16 && tid < 64) {
        const float* row = outred + ((T - 1) & 1) * 2048 + wg * 128;
        float s = row[tid * 2] + row[tid * 2 + 1];
        #pragma unroll
        for (int off = 32; off >= 1; off >>= 1) s += __shfl_xor(s, off);
        if (tid == 0) out[wg * T + (T - 1)] = s + bo;
    }
}

extern "C" void kernel_launch(void* const* d_in, const int* in_sizes, int n_in,
                              void* d_out, int out_size, void* d_ws, size_t ws_size,
                              hipStream_t stream) {
    const float* xin  = (const float*)d_in[0];
    const float* Wih1 = (const float*)d_in[1];
    const float* Whh1 = (const float*)d_in[2];
    const float* bih1 = (const float*)d_in[3];
    const float* bhh1 = (const float*)d_in[4];
    const float* Wih2 = (const float*)d_in[5];
    const float* Whh2 = (const float*)d_in[6];
    const float* bih2 = (const float*)d_in[7];
    const float* bhh2 = (const float*)d_in[8];
    const float* Wout = (const float*)d_in[9];
    const float* bout = (const float*)d_in[10];
    float* outp = (float*)d_out;
    int T = in_sizes[0] / 32;           // input is [16][T][2]

    unsigned* flags = (unsigned*)d_ws;                  // 256 packed u32 (rest zeroed too)
    float* h1g    = (float*)d_ws + 4096;                // [2][16][512]
    float* h2g    = h1g + 16384;                        // [2][16][512]
    float* outredp= h2g + 16384;                        // [2][16][128]

    hipLaunchKernelGGL(ws_init_kernel, dim3(1), dim3(256), 0, stream, flags);

    void* args[] = { &xin, &Wih1, &Whh1, &bih1, &bhh1, &Wih2, &Whh2, &bih2, &bhh2,
                     &Wout, &bout, &outp, &flags, &h1g, &h2g, &outredp, &T };
    hipLaunchCooperativeKernel((void*)lstm_kernel, dim3(NWG), dim3(NTHR), args, 0, stream);
}

// Round 6
// 131395.801 us; speedup vs baseline: 1.7346x; 1.7022x over previous
//
#include <hip/hip_runtime.h>
#include <math.h>

#define NWG  256
#define NTHR 256
#define AGT __HIP_MEMORY_SCOPE_AGENT

// LDS float offsets
#define O_W2  0        // [16][1024]
#define O_W1  16384    // [16][512]
#define O_U   24576    // union: hstage [8][1024]  /  red [128][68]  (8704 floats)
#define O_WX  33280    // [16][2]
#define O_B1  33312    // [16]
#define O_B2  33328    // [16]
#define O_WO  33344    // [4]
#define O_XS  33348    // [8][2]
#define O_GAT 33364    // [128]
#define O_C1  33492    // [32]
#define O_C2  33524    // [32]
#define O_HN  33556    // [32]
#define LDS_FLOATS 33600

union U64F2 { unsigned long long u; float f[2]; };

__global__ void ws_init_kernel(unsigned* flags) {
    for (int i = threadIdx.x; i < NWG * 16; i += blockDim.x) flags[i] = 0u;
}

__device__ __forceinline__ float sigm(float x) { return 1.0f / (1.0f + __expf(-x)); }
__device__ __forceinline__ float tanh_fast(float x) { return 2.0f / (1.0f + __expf(-2.0f * x)) - 1.0f; }

// Fence-free barrier: all cross-WG data goes through IC-coherent agent atomics,
// so ordering only needs the wave-level vmcnt drain before the flag store.
// NO buffer_wbl2 / buffer_inv cache walks (the R1/R5 __threadfence cost theory).
__device__ __forceinline__ void gbar(unsigned* flags, int wg, int tid, unsigned ph) {
    __syncthreads();                                     // publishes issued (wave 0)
    asm volatile("s_waitcnt vmcnt(0)" ::: "memory");     // each wave drains its own stores
    if (tid == 0)
        __hip_atomic_store(&flags[wg], ph, __ATOMIC_RELAXED, AGT);
    if (tid < 32) {                                      // 32 lanes x 2 u64 = 256 flags
        const unsigned long long* f64 = (const unsigned long long*)flags;
        bool done;
        do {
            unsigned long long v0 = __hip_atomic_load(&f64[2 * tid],     __ATOMIC_RELAXED, AGT);
            unsigned long long v1 = __hip_atomic_load(&f64[2 * tid + 1], __ATOMIC_RELAXED, AGT);
            done = ((unsigned)v0 >= ph) && ((unsigned)(v0 >> 32) >= ph) &&
                   ((unsigned)v1 >= ph) && ((unsigned)(v1 >> 32) >= ph);
            if (!__all(done)) __builtin_amdgcn_s_sleep(4);
        } while (!__all(done));
    }
    __syncthreads();
}

__global__ __launch_bounds__(NTHR, 1) void lstm_kernel(
    const float* __restrict__ xin,  const float* __restrict__ Wih1,
    const float* __restrict__ Whh1, const float* __restrict__ bih1,
    const float* __restrict__ bhh1, const float* __restrict__ Wih2,
    const float* __restrict__ Whh2, const float* __restrict__ bih2,
    const float* __restrict__ bhh2, const float* __restrict__ Wout,
    const float* __restrict__ bout, float* __restrict__ out,
    unsigned* __restrict__ flags, float* __restrict__ h1g,
    float* __restrict__ h2g, float* __restrict__ outred, int T)
{
    __shared__ float lds[LDS_FLOATS];
    const int tid = threadIdx.x;
    const int wg  = blockIdx.x;
    const int bh  = wg & 1;         // batch half: batches bh*8 .. bh*8+7
    const int jg  = wg >> 1;        // hidden-j group
    const int j0  = jg * 4;

    // ---- one-time: load weight slice into LDS ----
    for (int idx = tid; idx < 2048; idx += NTHR) {          // W1 = W_hh1 rows
        int r = idx >> 7, c4 = idx & 127;
        int grow = (r >> 2) * 512 + j0 + (r & 3);           // r = q*4+jj -> global row q*512+j
        *(float4*)&lds[O_W1 + r * 512 + c4 * 4] = *(const float4*)&Whh1[grow * 512 + c4 * 4];
    }
    for (int idx = tid; idx < 4096; idx += NTHR) {          // W2 = [W_ih2 | W_hh2] concat over K
        int r = idx >> 8, c4 = idx & 255;
        int grow = (r >> 2) * 512 + j0 + (r & 3);
        int k = c4 * 4;
        const float* src = (k < 512) ? &Wih2[grow * 512 + k] : &Whh2[grow * 512 + (k - 512)];
        *(float4*)&lds[O_W2 + r * 1024 + k] = *(const float4*)src;
    }
    if (tid < 32) {
        int r = tid >> 1, grow = (r >> 2) * 512 + j0 + (r & 3);
        lds[O_WX + tid] = Wih1[grow * 2 + (tid & 1)];
    }
    if (tid < 16) {
        int grow = (tid >> 2) * 512 + j0 + (tid & 3);
        lds[O_B1 + tid] = bih1[grow] + bhh1[grow];
        lds[O_B2 + tid] = bih2[grow] + bhh2[grow];
    }
    if (tid < 4) lds[O_WO + tid] = Wout[j0 + tid];
    if (tid < 32) { lds[O_C1 + tid] = 0.0f; lds[O_C2 + tid] = 0.0f; }
    const float bo = bout[0];
    __syncthreads();

    const int wv = tid >> 6;        // wave id -> row group (4 rows)
    const int ks = tid & 63;        // K-split lane
    unsigned ph = 0;

    for (int t = 0; t < T; ++t) {
        const int p = t & 1, pq = p ^ 1;

        // ================= phase A : layer 1 =================
        // out-duty for step t-1 (reads outred[pq], written before last barrier)
        if (wg < 16 && t > 0 && tid < 64) {
            const unsigned long long* row64 =
                (const unsigned long long*)(outred + pq * 2048 + wg * 128);
            U64F2 v; v.u = __hip_atomic_load(&row64[tid], __ATOMIC_RELAXED, AGT);
            float s = v.f[0] + v.f[1];
            #pragma unroll
            for (int off = 32; off >= 1; off >>= 1) s += __shfl_xor(s, off);
            if (tid == 0) out[wg * T + (t - 1)] = s + bo;
        }
        // stage h1_prev -> U[b][0..511] (row stride 1024), IC-coherent u64 loads
        if (t == 0) {
            for (int idx = tid; idx < 1024; idx += NTHR) {
                int b = idx >> 7, c4 = idx & 127;
                *(float4*)&lds[O_U + b * 1024 + c4 * 4] = make_float4(0.f, 0.f, 0.f, 0.f);
            }
        } else {
            const unsigned long long* src = (const unsigned long long*)(h1g + pq * 8192);
            for (int idx = tid; idx < 2048; idx += NTHR) {
                int b = idx >> 8, pos = idx & 255;      // u64 units, 256 per batch row
                unsigned long long v = __hip_atomic_load(&src[(bh * 8 + b) * 256 + pos],
                                                         __ATOMIC_RELAXED, AGT);
                *(unsigned long long*)&lds[O_U + b * 1024 + pos * 2] = v;
            }
        }
        if (tid < 16) {
            int b = tid >> 1, cm = tid & 1;
            lds[O_XS + tid] = xin[((bh * 8 + b) * (long)T + t) * 2 + cm];
        }
        __syncthreads();

        {   // gates: rows (4*wv..4*wv+3) x 8 batches, K=512 split over 64 lanes
            float acc[4][8];
            #pragma unroll
            for (int r = 0; r < 4; ++r)
                #pragma unroll
                for (int b = 0; b < 8; ++b) acc[r][b] = 0.0f;
            const float* Wb = &lds[O_W1 + wv * 4 * 512];
            #pragma unroll
            for (int c = 0; c < 2; ++c) {
                int k = ks * 4 + c * 256;
                float4 w0 = *(const float4*)&Wb[0 * 512 + k];
                float4 w1 = *(const float4*)&Wb[1 * 512 + k];
                float4 w2 = *(const float4*)&Wb[2 * 512 + k];
                float4 w3 = *(const float4*)&Wb[3 * 512 + k];
                #pragma unroll
                for (int b = 0; b < 8; ++b) {
                    float4 h = *(const float4*)&lds[O_U + b * 1024 + k];
                    acc[0][b] = fmaf(w0.x,h.x,fmaf(w0.y,h.y,fmaf(w0.z,h.z,fmaf(w0.w,h.w,acc[0][b]))));
                    acc[1][b] = fmaf(w1.x,h.x,fmaf(w1.y,h.y,fmaf(w1.z,h.z,fmaf(w1.w,h.w,acc[1][b]))));
                    acc[2][b] = fmaf(w2.x,h.x,fmaf(w2.y,h.y,fmaf(w2.z,h.z,fmaf(w2.w,h.w,acc[2][b]))));
                    acc[3][b] = fmaf(w3.x,h.x,fmaf(w3.y,h.y,fmaf(w3.z,h.z,fmaf(w3.w,h.w,acc[3][b]))));
                }
            }
            __syncthreads();            // done reading hstage; U becomes red[]
            #pragma unroll
            for (int r = 0; r < 4; ++r)
                #pragma unroll
                for (int b = 0; b < 8; ++b)
                    lds[O_U + ((wv * 4 + r) * 8 + b) * 68 + ks] = acc[r][b];
        }
        __syncthreads();
        {   // K-reduce + bias + x-part
            int o = tid >> 1, hf = tid & 1;
            const float* rr = &lds[O_U + o * 68 + hf * 32];
            float s = 0.0f;
            #pragma unroll
            for (int c = 0; c < 8; ++c) { float4 v = *(const float4*)&rr[c * 4]; s += v.x + v.y + v.z + v.w; }
            s += __shfl_xor(s, 1);
            if (hf == 0) {
                int r = o >> 3, b = o & 7;
                lds[O_GAT + o] = s + lds[O_B1 + r]
                               + lds[O_WX + r * 2]     * lds[O_XS + b * 2]
                               + lds[O_WX + r * 2 + 1] * lds[O_XS + b * 2 + 1];
            }
        }
        __syncthreads();
        if (tid < 32) {     // activations + cell update + publish h1 (IC atomic)
            int jj = tid >> 3, b = tid & 7;
            float gi = sigm(lds[O_GAT + (0 * 4 + jj) * 8 + b]);
            float gf = sigm(lds[O_GAT + (1 * 4 + jj) * 8 + b]);
            float gg = tanh_fast(lds[O_GAT + (2 * 4 + jj) * 8 + b]);
            float go = sigm(lds[O_GAT + (3 * 4 + jj) * 8 + b]);
            float c  = gf * lds[O_C1 + tid] + gi * gg;
            lds[O_C1 + tid] = c;
            __hip_atomic_store(&h1g[p * 8192 + (bh * 8 + b) * 512 + j0 + jj],
                               go * tanh_fast(c), __ATOMIC_RELAXED, AGT);
        }
        gbar(flags, wg, tid, ++ph);

        // ================= phase B : layer 2 =================
        {   // stage [h1(t) | h2(t-1)] via IC-coherent u64 loads
            const unsigned long long* h1s = (const unsigned long long*)(h1g + p  * 8192);
            const unsigned long long* h2s = (const unsigned long long*)(h2g + pq * 8192);
            for (int idx = tid; idx < 4096; idx += NTHR) {
                int b = idx >> 9, pos = idx & 511;      // u64 units, 512 per [h1|h2] row
                unsigned long long v;
                if (pos < 256)
                    v = __hip_atomic_load(&h1s[(bh * 8 + b) * 256 + pos], __ATOMIC_RELAXED, AGT);
                else if (t == 0)
                    v = 0ull;
                else
                    v = __hip_atomic_load(&h2s[(bh * 8 + b) * 256 + (pos - 256)], __ATOMIC_RELAXED, AGT);
                *(unsigned long long*)&lds[O_U + b * 1024 + pos * 2] = v;
            }
        }
        __syncthreads();
        {
            float acc[4][8];
            #pragma unroll
            for (int r = 0; r < 4; ++r)
                #pragma unroll
                for (int b = 0; b < 8; ++b) acc[r][b] = 0.0f;
            const float* Wb = &lds[O_W2 + wv * 4 * 1024];
            #pragma unroll
            for (int c = 0; c < 4; ++c) {
                int k = ks * 4 + c * 256;
                float4 w0 = *(const float4*)&Wb[0 * 1024 + k];
                float4 w1 = *(const float4*)&Wb[1 * 1024 + k];
                float4 w2 = *(const float4*)&Wb[2 * 1024 + k];
                float4 w3 = *(const float4*)&Wb[3 * 1024 + k];
                #pragma unroll
                for (int b = 0; b < 8; ++b) {
                    float4 h = *(const float4*)&lds[O_U + b * 1024 + k];
                    acc[0][b] = fmaf(w0.x,h.x,fmaf(w0.y,h.y,fmaf(w0.z,h.z,fmaf(w0.w,h.w,acc[0][b]))));
                    acc[1][b] = fmaf(w1.x,h.x,fmaf(w1.y,h.y,fmaf(w1.z,h.z,fmaf(w1.w,h.w,acc[1][b]))));
                    acc[2][b] = fmaf(w2.x,h.x,fmaf(w2.y,h.y,fmaf(w2.z,h.z,fmaf(w2.w,h.w,acc[2][b]))));
                    acc[3][b] = fmaf(w3.x,h.x,fmaf(w3.y,h.y,fmaf(w3.z,h.z,fmaf(w3.w,h.w,acc[3][b]))));
                }
            }
            __syncthreads();
            #pragma unroll
            for (int r = 0; r < 4; ++r)
                #pragma unroll
                for (int b = 0; b < 8; ++b)
                    lds[O_U + ((wv * 4 + r) * 8 + b) * 68 + ks] = acc[r][b];
        }
        __syncthreads();
        {
            int o = tid >> 1, hf = tid & 1;
            const float* rr = &lds[O_U + o * 68 + hf * 32];
            float s = 0.0f;
            #pragma unroll
            for (int c = 0; c < 8; ++c) { float4 v = *(const float4*)&rr[c * 4]; s += v.x + v.y + v.z + v.w; }
            s += __shfl_xor(s, 1);
            if (hf == 0) {
                int r = o >> 3;
                lds[O_GAT + o] = s + lds[O_B2 + r];
            }
        }
        __syncthreads();
        if (tid < 32) {
            int jj = tid >> 3, b = tid & 7;
            float gi = sigm(lds[O_GAT + (0 * 4 + jj) * 8 + b]);
            float gf = sigm(lds[O_GAT + (1 * 4 + jj) * 8 + b]);
            float gg = tanh_fast(lds[O_GAT + (2 * 4 + jj) * 8 + b]);
            float go = sigm(lds[O_GAT + (3 * 4 + jj) * 8 + b]);
            float c  = gf * lds[O_C2 + tid] + gi * gg;
            lds[O_C2 + tid] = c;
            float h = go * tanh_fast(c);
            __hip_atomic_store(&h2g[p * 8192 + (bh * 8 + b) * 512 + j0 + jj],
                               h, __ATOMIC_RELAXED, AGT);
            lds[O_HN + tid] = lds[O_WO + jj] * h;      // product for W_out dot
        }
        __syncthreads();
        if (tid < 8) {      // per-batch partial of W_out dot for this j-group
            float pr = lds[O_HN + tid] + lds[O_HN + 8 + tid] + lds[O_HN + 16 + tid] + lds[O_HN + 24 + tid];
            __hip_atomic_store(&outred[p * 2048 + (bh * 8 + tid) * 128 + jg],
                               pr, __ATOMIC_RELAXED, AGT);
        }
        gbar(flags, wg, tid, ++ph);
    }

    // tail: output for t = T-1
    if (wg < 16 && tid < 64) {
        const unsigned long long* row64 =
            (const unsigned long long*)(outred + ((T - 1) & 1) * 2048 + wg * 128);
        U64F2 v; v.u = __hip_atomic_load(&row64[tid], __ATOMIC_RELAXED, AGT);
        float s = v.f[0] + v.f[1];
        #pragma unroll
        for (int off = 32; off >= 1; off >>= 1) s += __shfl_xor(s, off);
        if (tid == 0) out[wg * T + (T - 1)] = s + bo;
    }
}

extern "C" void kernel_launch(void* const* d_in, const int* in_sizes, int n_in,
                              void* d_out, int out_size, void* d_ws, size_t ws_size,
                              hipStream_t stream) {
    const float* xin  = (const float*)d_in[0];
    const float* Wih1 = (const float*)d_in[1];
    const float* Whh1 = (const float*)d_in[2];
    const float* bih1 = (const float*)d_in[3];
    const float* bhh1 = (const float*)d_in[4];
    const float* Wih2 = (const float*)d_in[5];
    const float* Whh2 = (const float*)d_in[6];
    const float* bih2 = (const float*)d_in[7];
    const float* bhh2 = (const float*)d_in[8];
    const float* Wout = (const float*)d_in[9];
    const float* bout = (const float*)d_in[10];
    float* outp = (float*)d_out;
    int T = in_sizes[0] / 32;           // input is [16][T][2]

    unsigned* flags = (unsigned*)d_ws;                  // 256 packed u32 (region zeroed)
    float* h1g    = (float*)d_ws + 4096;                // [2][16][512]
    float* h2g    = h1g + 16384;                        // [2][16][512]
    float* outredp= h2g + 16384;                        // [2][16][128]

    hipLaunchKernelGGL(ws_init_kernel, dim3(1), dim3(256), 0, stream, flags);

    void* args[] = { &xin, &Wih1, &Whh1, &bih1, &bhh1, &Wih2, &Whh2, &bih2, &bhh2,
                     &Wout, &bout, &outp, &flags, &h1g, &h2g, &outredp, &T };
    hipLaunchCooperativeKernel((void*)lstm_kernel, dim3(NWG), dim3(NTHR), args, 0, stream);
}

// Round 7
// 105071.252 us; speedup vs baseline: 2.1691x; 1.2505x over previous
//
#include <hip/hip_runtime.h>
#include <math.h>

#define NWG  256
#define NTHR 256
#define AGT __HIP_MEMORY_SCOPE_AGENT

// LDS float offsets
#define O_W2  0        // [16][1024]
#define O_W1  16384    // [16][512]
#define O_U   24576    // union: hstage [8][1024]  /  red [128][68]  (8704 floats)
#define O_WX  33280    // [16][2]
#define O_B1  33312    // [16]
#define O_B2  33328    // [16]
#define O_WO  33344    // [4]
#define O_XS  33348    // [8][2]
#define O_GAT 33364    // [128]
#define O_C1  33492    // [32]
#define O_C2  33524    // [32]
#define O_HN  33556    // [32]
#define LDS_FLOATS 33600

union U64F2 { unsigned long long u; float f[2]; };

__global__ void ws_init_kernel(unsigned* flags) {
    for (int i = threadIdx.x; i < NWG * 16; i += blockDim.x) flags[i] = 0u;
}

__device__ __forceinline__ float sigm(float x) { return 1.0f / (1.0f + __expf(-x)); }
__device__ __forceinline__ float tanh_fast(float x) { return 2.0f / (1.0f + __expf(-2.0f * x)) - 1.0f; }

// Fence-free barrier (validated R6): IC-coherent agent atomics for data,
// vmcnt drain, packed-flag wave-0 poll. No cache-maintenance instructions.
__device__ __forceinline__ void gbar(unsigned* flags, int wg, int tid, unsigned ph) {
    __syncthreads();                                     // WG work complete
    asm volatile("s_waitcnt vmcnt(0)" ::: "memory");     // drain this wave's stores
    if (tid == 0)
        __hip_atomic_store(&flags[wg], ph, __ATOMIC_RELAXED, AGT);
    if (tid < 32) {                                      // 32 lanes x 2 u64 = 256 flags
        const unsigned long long* f64 = (const unsigned long long*)flags;
        bool done;
        do {
            unsigned long long v0 = __hip_atomic_load(&f64[2 * tid],     __ATOMIC_RELAXED, AGT);
            unsigned long long v1 = __hip_atomic_load(&f64[2 * tid + 1], __ATOMIC_RELAXED, AGT);
            done = ((unsigned)v0 >= ph) && ((unsigned)(v0 >> 32) >= ph) &&
                   ((unsigned)v1 >= ph) && ((unsigned)(v1 >> 32) >= ph);
            if (!__all(done)) __builtin_amdgcn_s_sleep(4);
        } while (!__all(done));
    }
    __syncthreads();
}

__global__ __launch_bounds__(NTHR, 1) void lstm_kernel(
    const float* __restrict__ xin,  const float* __restrict__ Wih1,
    const float* __restrict__ Whh1, const float* __restrict__ bih1,
    const float* __restrict__ bhh1, const float* __restrict__ Wih2,
    const float* __restrict__ Whh2, const float* __restrict__ bih2,
    const float* __restrict__ bhh2, const float* __restrict__ Wout,
    const float* __restrict__ bout, float* __restrict__ out,
    unsigned* __restrict__ flags, float* __restrict__ h1g,
    float* __restrict__ h2g, float* __restrict__ outred, int T)
{
    __shared__ float lds[LDS_FLOATS];
    const int tid = threadIdx.x;
    const int wg  = blockIdx.x;
    const int bh  = wg & 1;         // batch half: batches bh*8 .. bh*8+7
    const int jg  = wg >> 1;        // hidden-j group
    const int j0  = jg * 4;

    // ---- one-time: load weight slice into LDS ----
    for (int idx = tid; idx < 2048; idx += NTHR) {          // W1 = W_hh1 rows
        int r = idx >> 7, c4 = idx & 127;
        int grow = (r >> 2) * 512 + j0 + (r & 3);           // r = q*4+jj -> global row q*512+j
        *(float4*)&lds[O_W1 + r * 512 + c4 * 4] = *(const float4*)&Whh1[grow * 512 + c4 * 4];
    }
    for (int idx = tid; idx < 4096; idx += NTHR) {          // W2 = [W_ih2 | W_hh2] concat over K
        int r = idx >> 8, c4 = idx & 255;
        int grow = (r >> 2) * 512 + j0 + (r & 3);
        int k = c4 * 4;
        const float* src = (k < 512) ? &Wih2[grow * 512 + k] : &Whh2[grow * 512 + (k - 512)];
        *(float4*)&lds[O_W2 + r * 1024 + k] = *(const float4*)src;
    }
    if (tid < 32) {
        int r = tid >> 1, grow = (r >> 2) * 512 + j0 + (r & 3);
        lds[O_WX + tid] = Wih1[grow * 2 + (tid & 1)];
    }
    if (tid < 16) {
        int grow = (tid >> 2) * 512 + j0 + (tid & 3);
        lds[O_B1 + tid] = bih1[grow] + bhh1[grow];
        lds[O_B2 + tid] = bih2[grow] + bhh2[grow];
    }
    if (tid < 4) lds[O_WO + tid] = Wout[j0 + tid];
    if (tid < 32) { lds[O_C1 + tid] = 0.0f; lds[O_C2 + tid] = 0.0f; }
    const float bo = bout[0];
    __syncthreads();

    const int wv = tid >> 6;        // wave id -> row group (4 rows)
    const int ks = tid & 63;        // K-split lane
    unsigned ph = 0;

    for (int t = 0; t < T; ++t) {
        const int p = t & 1, pq = p ^ 1;

        // ================= phase A : layer 1 =================
        // stage h1_prev -> U[b][0..511] (row stride 1024), IC-coherent u64 loads
        if (t == 0) {
            for (int idx = tid; idx < 1024; idx += NTHR) {
                int b = idx >> 7, c4 = idx & 127;
                *(float4*)&lds[O_U + b * 1024 + c4 * 4] = make_float4(0.f, 0.f, 0.f, 0.f);
            }
        } else {
            const unsigned long long* src = (const unsigned long long*)(h1g + pq * 8192);
            for (int idx = tid; idx < 2048; idx += NTHR) {
                int b = idx >> 8, pos = idx & 255;      // u64 units, 256 per batch row
                unsigned long long v = __hip_atomic_load(&src[(bh * 8 + b) * 256 + pos],
                                                         __ATOMIC_RELAXED, AGT);
                *(unsigned long long*)&lds[O_U + b * 1024 + pos * 2] = v;
            }
        }
        if (tid < 16) {
            int b = tid >> 1, cm = tid & 1;
            lds[O_XS + tid] = xin[((bh * 8 + b) * (long)T + t) * 2 + cm];
        }
        __syncthreads();

        {   // gates: rows (4*wv..4*wv+3) x 8 batches, K=512 split over 64 lanes
            float acc[4][8];
            #pragma unroll
            for (int r = 0; r < 4; ++r)
                #pragma unroll
                for (int b = 0; b < 8; ++b) acc[r][b] = 0.0f;
            const float* Wb = &lds[O_W1 + wv * 4 * 512];
            #pragma unroll
            for (int c = 0; c < 2; ++c) {
                int k = ks * 4 + c * 256;
                float4 w0 = *(const float4*)&Wb[0 * 512 + k];
                float4 w1 = *(const float4*)&Wb[1 * 512 + k];
                float4 w2 = *(const float4*)&Wb[2 * 512 + k];
                float4 w3 = *(const float4*)&Wb[3 * 512 + k];
                #pragma unroll
                for (int b = 0; b < 8; ++b) {
                    float4 h = *(const float4*)&lds[O_U + b * 1024 + k];
                    acc[0][b] = fmaf(w0.x,h.x,fmaf(w0.y,h.y,fmaf(w0.z,h.z,fmaf(w0.w,h.w,acc[0][b]))));
                    acc[1][b] = fmaf(w1.x,h.x,fmaf(w1.y,h.y,fmaf(w1.z,h.z,fmaf(w1.w,h.w,acc[1][b]))));
                    acc[2][b] = fmaf(w2.x,h.x,fmaf(w2.y,h.y,fmaf(w2.z,h.z,fmaf(w2.w,h.w,acc[2][b]))));
                    acc[3][b] = fmaf(w3.x,h.x,fmaf(w3.y,h.y,fmaf(w3.z,h.z,fmaf(w3.w,h.w,acc[3][b]))));
                }
            }
            __syncthreads();            // done reading hstage; U becomes red[]
            #pragma unroll
            for (int r = 0; r < 4; ++r)
                #pragma unroll
                for (int b = 0; b < 8; ++b)
                    lds[O_U + ((wv * 4 + r) * 8 + b) * 68 + ks] = acc[r][b];
        }
        __syncthreads();
        {   // K-reduce + bias + x-part
            int o = tid >> 1, hf = tid & 1;
            const float* rr = &lds[O_U + o * 68 + hf * 32];
            float s = 0.0f;
            #pragma unroll
            for (int c = 0; c < 8; ++c) { float4 v = *(const float4*)&rr[c * 4]; s += v.x + v.y + v.z + v.w; }
            s += __shfl_xor(s, 1);
            if (hf == 0) {
                int r = o >> 3, b = o & 7;
                lds[O_GAT + o] = s + lds[O_B1 + r]
                               + lds[O_WX + r * 2]     * lds[O_XS + b * 2]
                               + lds[O_WX + r * 2 + 1] * lds[O_XS + b * 2 + 1];
            }
        }
        __syncthreads();
        if (tid < 32) {     // activations + cell update + publish h1 (IC atomic)
            int jj = tid >> 3, b = tid & 7;
            float gi = sigm(lds[O_GAT + (0 * 4 + jj) * 8 + b]);
            float gf = sigm(lds[O_GAT + (1 * 4 + jj) * 8 + b]);
            float gg = tanh_fast(lds[O_GAT + (2 * 4 + jj) * 8 + b]);
            float go = sigm(lds[O_GAT + (3 * 4 + jj) * 8 + b]);
            float c  = gf * lds[O_C1 + tid] + gi * gg;
            lds[O_C1 + tid] = c;
            __hip_atomic_store(&h1g[p * 8192 + (bh * 8 + b) * 512 + j0 + jj],
                               go * tanh_fast(c), __ATOMIC_RELAXED, AGT);
        }
        gbar(flags, wg, tid, ++ph);   // THE one barrier per step: h1_t broadcast

        // ================= phase B : layer 2 (no barrier after) =================
        // out duty moved here: y_{t-1} from outred[pq] (written in B(t-1);
        // bar_t sits between write and read -> visible). WAR on outred[pq] is
        // safe: next write to this parity is B(t+1), gated by bar_{t+1} which
        // subsumes completion of this read.
        if (wg < 16 && t > 0 && tid < 64) {
            const unsigned long long* row64 =
                (const unsigned long long*)(outred + pq * 2048 + wg * 128);
            U64F2 v; v.u = __hip_atomic_load(&row64[tid], __ATOMIC_RELAXED, AGT);
            float s = v.f[0] + v.f[1];
            #pragma unroll
            for (int off = 32; off >= 1; off >>= 1) s += __shfl_xor(s, off);
            if (tid == 0) out[wg * T + (t - 1)] = s + bo;
        }
        {   // stage [h1(t) | h2(t-1)] via IC-coherent u64 loads
            const unsigned long long* h1s = (const unsigned long long*)(h1g + p  * 8192);
            const unsigned long long* h2s = (const unsigned long long*)(h2g + pq * 8192);
            for (int idx = tid; idx < 4096; idx += NTHR) {
                int b = idx >> 9, pos = idx & 511;      // u64 units, 512 per [h1|h2] row
                unsigned long long v;
                if (pos < 256)
                    v = __hip_atomic_load(&h1s[(bh * 8 + b) * 256 + pos], __ATOMIC_RELAXED, AGT);
                else if (t == 0)
                    v = 0ull;
                else
                    v = __hip_atomic_load(&h2s[(bh * 8 + b) * 256 + (pos - 256)], __ATOMIC_RELAXED, AGT);
                *(unsigned long long*)&lds[O_U + b * 1024 + pos * 2] = v;
            }
        }
        __syncthreads();
        {
            float acc[4][8];
            #pragma unroll
            for (int r = 0; r < 4; ++r)
                #pragma unroll
                for (int b = 0; b < 8; ++b) acc[r][b] = 0.0f;
            const float* Wb = &lds[O_W2 + wv * 4 * 1024];
            #pragma unroll
            for (int c = 0; c < 4; ++c) {
                int k = ks * 4 + c * 256;
                float4 w0 = *(const float4*)&Wb[0 * 1024 + k];
                float4 w1 = *(const float4*)&Wb[1 * 1024 + k];
                float4 w2 = *(const float4*)&Wb[2 * 1024 + k];
                float4 w3 = *(const float4*)&Wb[3 * 1024 + k];
                #pragma unroll
                for (int b = 0; b < 8; ++b) {
                    float4 h = *(const float4*)&lds[O_U + b * 1024 + k];
                    acc[0][b] = fmaf(w0.x,h.x,fmaf(w0.y,h.y,fmaf(w0.z,h.z,fmaf(w0.w,h.w,acc[0][b]))));
                    acc[1][b] = fmaf(w1.x,h.x,fmaf(w1.y,h.y,fmaf(w1.z,h.z,fmaf(w1.w,h.w,acc[1][b]))));
                    acc[2][b] = fmaf(w2.x,h.x,fmaf(w2.y,h.y,fmaf(w2.z,h.z,fmaf(w2.w,h.w,acc[2][b]))));
                    acc[3][b] = fmaf(w3.x,h.x,fmaf(w3.y,h.y,fmaf(w3.z,h.z,fmaf(w3.w,h.w,acc[3][b]))));
                }
            }
            __syncthreads();
            #pragma unroll
            for (int r = 0; r < 4; ++r)
                #pragma unroll
                for (int b = 0; b < 8; ++b)
                    lds[O_U + ((wv * 4 + r) * 8 + b) * 68 + ks] = acc[r][b];
        }
        __syncthreads();
        {
            int o = tid >> 1, hf = tid & 1;
            const float* rr = &lds[O_U + o * 68 + hf * 32];
            float s = 0.0f;
            #pragma unroll
            for (int c = 0; c < 8; ++c) { float4 v = *(const float4*)&rr[c * 4]; s += v.x + v.y + v.z + v.w; }
            s += __shfl_xor(s, 1);
            if (hf == 0) {
                int r = o >> 3;
                lds[O_GAT + o] = s + lds[O_B2 + r];
            }
        }
        __syncthreads();
        if (tid < 32) {
            int jj = tid >> 3, b = tid & 7;
            float gi = sigm(lds[O_GAT + (0 * 4 + jj) * 8 + b]);
            float gf = sigm(lds[O_GAT + (1 * 4 + jj) * 8 + b]);
            float gg = tanh_fast(lds[O_GAT + (2 * 4 + jj) * 8 + b]);
            float go = sigm(lds[O_GAT + (3 * 4 + jj) * 8 + b]);
            float c  = gf * lds[O_C2 + tid] + gi * gg;
            lds[O_C2 + tid] = c;
            float h = go * tanh_fast(c);
            __hip_atomic_store(&h2g[p * 8192 + (bh * 8 + b) * 512 + j0 + jj],
                               h, __ATOMIC_RELAXED, AGT);
            lds[O_HN + tid] = lds[O_WO + jj] * h;      // product for W_out dot
        }
        __syncthreads();
        if (tid < 8) {      // per-batch partial of W_out dot for this j-group
            float pr = lds[O_HN + tid] + lds[O_HN + 8 + tid] + lds[O_HN + 16 + tid] + lds[O_HN + 24 + tid];
            __hip_atomic_store(&outred[p * 2048 + (bh * 8 + tid) * 128 + jg],
                               pr, __ATOMIC_RELAXED, AGT);
        }
        // no barrier here — next A-barrier (bar_{t+1}) covers B(t)'s publishes
    }

    // final barrier so the tail sees every WG's B(T-1) outred writes
    gbar(flags, wg, tid, ++ph);

    // tail: output for t = T-1
    if (wg < 16 && tid < 64) {
        const unsigned long long* row64 =
            (const unsigned long long*)(outred + ((T - 1) & 1) * 2048 + wg * 128);
        U64F2 v; v.u = __hip_atomic_load(&row64[tid], __ATOMIC_RELAXED, AGT);
        float s = v.f[0] + v.f[1];
        #pragma unroll
        for (int off = 32; off >= 1; off >>= 1) s += __shfl_xor(s, off);
        if (tid == 0) out[wg * T + (T - 1)] = s + bo;
    }
}

extern "C" void kernel_launch(void* const* d_in, const int* in_sizes, int n_in,
                              void* d_out, int out_size, void* d_ws, size_t ws_size,
                              hipStream_t stream) {
    const float* xin  = (const float*)d_in[0];
    const float* Wih1 = (const float*)d_in[1];
    const float* Whh1 = (const float*)d_in[2];
    const float* bih1 = (const float*)d_in[3];
    const float* bhh1 = (const float*)d_in[4];
    const float* Wih2 = (const float*)d_in[5];
    const float* Whh2 = (const float*)d_in[6];
    const float* bih2 = (const float*)d_in[7];
    const float* bhh2 = (const float*)d_in[8];
    const float* Wout = (const float*)d_in[9];
    const float* bout = (const float*)d_in[10];
    float* outp = (float*)d_out;
    int T = in_sizes[0] / 32;           // input is [16][T][2]

    unsigned* flags = (unsigned*)d_ws;                  // 256 packed u32 (region zeroed)
    float* h1g    = (float*)d_ws + 4096;                // [2][16][512]
    float* h2g    = h1g + 16384;                        // [2][16][512]
    float* outredp= h2g + 16384;                        // [2][16][128]

    hipLaunchKernelGGL(ws_init_kernel, dim3(1), dim3(256), 0, stream, flags);

    void* args[] = { &xin, &Wih1, &Whh1, &bih1, &bhh1, &Wih2, &Whh2, &bih2, &bhh2,
                     &Wout, &bout, &outp, &flags, &h1g, &h2g, &outredp, &T };
    hipLaunchCooperativeKernel((void*)lstm_kernel, dim3(NWG), dim3(NTHR), args, 0, stream);
}

// Round 8
// 74892.743 us; speedup vs baseline: 3.0432x; 1.4030x over previous
//
#include <hip/hip_runtime.h>
#include <math.h>

#define NWG  256
#define NTHR 256
#define AGT __HIP_MEMORY_SCOPE_AGENT

// LDS float offsets
#define O_W2  0        // [16][1024]
#define O_W1  16384    // [16][512]
#define O_U   24576    // union: hstage [8][1024]  /  red [128][68]  (8704 floats)
#define O_WX  33280    // [16][2]
#define O_B1  33312    // [16]
#define O_B2  33328    // [16]
#define O_WO  33344    // [4]
#define O_XS  33348    // [8][2]
#define O_GAT 33364    // [128]
#define O_C1  33492    // [32]
#define O_C2  33524    // [32]
#define O_HN  33556    // [32]
#define LDS_FLOATS 33600

union U64F2 { unsigned long long u; float f[2]; };

__global__ void ws_init_kernel(unsigned* flags) {
    for (int i = threadIdx.x; i < NWG * 16; i += blockDim.x) flags[i] = 0u;
}

__device__ __forceinline__ float sigm(float x) { return 1.0f / (1.0f + __expf(-x)); }
__device__ __forceinline__ float tanh_fast(float x) { return 2.0f / (1.0f + __expf(-2.0f * x)) - 1.0f; }

// Fence-free barrier (validated R6/R7): IC-coherent agent atomics for data,
// vmcnt drain, packed-flag wave-0 poll. No cache-maintenance instructions.
__device__ __forceinline__ void gbar(unsigned* flags, int wg, int tid, unsigned ph) {
    __syncthreads();                                     // WG work complete
    asm volatile("s_waitcnt vmcnt(0)" ::: "memory");     // drain this wave's stores
    if (tid == 0)
        __hip_atomic_store(&flags[wg], ph, __ATOMIC_RELAXED, AGT);
    if (tid < 32) {                                      // 32 lanes x 2 u64 = 256 flags
        const unsigned long long* f64 = (const unsigned long long*)flags;
        bool done;
        do {
            unsigned long long v0 = __hip_atomic_load(&f64[2 * tid],     __ATOMIC_RELAXED, AGT);
            unsigned long long v1 = __hip_atomic_load(&f64[2 * tid + 1], __ATOMIC_RELAXED, AGT);
            done = ((unsigned)v0 >= ph) && ((unsigned)(v0 >> 32) >= ph) &&
                   ((unsigned)v1 >= ph) && ((unsigned)(v1 >> 32) >= ph);
            if (!__all(done)) __builtin_amdgcn_s_sleep(4);
        } while (!__all(done));
    }
    __syncthreads();
}

__global__ __launch_bounds__(NTHR, 1) void lstm_kernel(
    const float* __restrict__ xin,  const float* __restrict__ Wih1,
    const float* __restrict__ Whh1, const float* __restrict__ bih1,
    const float* __restrict__ bhh1, const float* __restrict__ Wih2,
    const float* __restrict__ Whh2, const float* __restrict__ bih2,
    const float* __restrict__ bhh2, const float* __restrict__ Wout,
    const float* __restrict__ bout, float* __restrict__ out,
    unsigned* __restrict__ flags, float* __restrict__ h1g,
    float* __restrict__ h2g, float* __restrict__ outred, int T)
{
    __shared__ float lds[LDS_FLOATS];
    const int tid = threadIdx.x;
    const int wg  = blockIdx.x;
    const int bh  = wg & 1;         // batch half: batches bh*8 .. bh*8+7
    const int jg  = wg >> 1;        // hidden-j group
    const int j0  = jg * 4;

    // ---- one-time: load weight slice into LDS ----
    for (int idx = tid; idx < 2048; idx += NTHR) {          // W1 = W_hh1 rows
        int r = idx >> 7, c4 = idx & 127;
        int grow = (r >> 2) * 512 + j0 + (r & 3);           // r = q*4+jj -> global row q*512+j
        *(float4*)&lds[O_W1 + r * 512 + c4 * 4] = *(const float4*)&Whh1[grow * 512 + c4 * 4];
    }
    for (int idx = tid; idx < 4096; idx += NTHR) {          // W2 = [W_ih2 | W_hh2] concat over K
        int r = idx >> 8, c4 = idx & 255;
        int grow = (r >> 2) * 512 + j0 + (r & 3);
        int k = c4 * 4;
        const float* src = (k < 512) ? &Wih2[grow * 512 + k] : &Whh2[grow * 512 + (k - 512)];
        *(float4*)&lds[O_W2 + r * 1024 + k] = *(const float4*)src;
    }
    if (tid < 32) {
        int r = tid >> 1, grow = (r >> 2) * 512 + j0 + (r & 3);
        lds[O_WX + tid] = Wih1[grow * 2 + (tid & 1)];
    }
    if (tid < 16) {
        int grow = (tid >> 2) * 512 + j0 + (tid & 3);
        lds[O_B1 + tid] = bih1[grow] + bhh1[grow];
        lds[O_B2 + tid] = bih2[grow] + bhh2[grow];
    }
    if (tid < 4) lds[O_WO + tid] = Wout[j0 + tid];
    if (tid < 32) { lds[O_C1 + tid] = 0.0f; lds[O_C2 + tid] = 0.0f; }
    const float bo = bout[0];
    __syncthreads();

    const int wv = tid >> 6;        // wave id -> row group (4 rows)
    const int ks = tid & 63;        // K-split lane
    unsigned ph = 0;

    for (int t = 0; t < T; ++t) {
        const int p = t & 1, pq = p ^ 1;

        // ================= phase A : layer 1 =================
        // stage h1_prev -> U[b][0..511]; BATCHED: all 8 IC loads issued before
        // any LDS write, so latencies overlap (one vmcnt drain, not 8 round-trips)
        if (t == 0) {
            for (int idx = tid; idx < 1024; idx += NTHR) {
                int b = idx >> 7, c4 = idx & 127;
                *(float4*)&lds[O_U + b * 1024 + c4 * 4] = make_float4(0.f, 0.f, 0.f, 0.f);
            }
        } else {
            const unsigned long long* src = (const unsigned long long*)(h1g + pq * 8192);
            unsigned long long tmp[8];
            #pragma unroll
            for (int i = 0; i < 8; ++i) {
                int idx = tid + i * NTHR;
                int b = idx >> 8, pos = idx & 255;      // u64 units, 256 per batch row
                tmp[i] = __hip_atomic_load(&src[(bh * 8 + b) * 256 + pos],
                                           __ATOMIC_RELAXED, AGT);
            }
            #pragma unroll
            for (int i = 0; i < 8; ++i) {
                int idx = tid + i * NTHR;
                int b = idx >> 8, pos = idx & 255;
                *(unsigned long long*)&lds[O_U + b * 1024 + pos * 2] = tmp[i];
            }
        }
        if (tid < 16) {
            int b = tid >> 1, cm = tid & 1;
            lds[O_XS + tid] = xin[((bh * 8 + b) * (long)T + t) * 2 + cm];
        }
        __syncthreads();

        {   // gates: rows (4*wv..4*wv+3) x 8 batches, K=512 split over 64 lanes
            float acc[4][8];
            #pragma unroll
            for (int r = 0; r < 4; ++r)
                #pragma unroll
                for (int b = 0; b < 8; ++b) acc[r][b] = 0.0f;
            const float* Wb = &lds[O_W1 + wv * 4 * 512];
            #pragma unroll
            for (int c = 0; c < 2; ++c) {
                int k = ks * 4 + c * 256;
                float4 w0 = *(const float4*)&Wb[0 * 512 + k];
                float4 w1 = *(const float4*)&Wb[1 * 512 + k];
                float4 w2 = *(const float4*)&Wb[2 * 512 + k];
                float4 w3 = *(const float4*)&Wb[3 * 512 + k];
                #pragma unroll
                for (int b = 0; b < 8; ++b) {
                    float4 h = *(const float4*)&lds[O_U + b * 1024 + k];
                    acc[0][b] = fmaf(w0.x,h.x,fmaf(w0.y,h.y,fmaf(w0.z,h.z,fmaf(w0.w,h.w,acc[0][b]))));
                    acc[1][b] = fmaf(w1.x,h.x,fmaf(w1.y,h.y,fmaf(w1.z,h.z,fmaf(w1.w,h.w,acc[1][b]))));
                    acc[2][b] = fmaf(w2.x,h.x,fmaf(w2.y,h.y,fmaf(w2.z,h.z,fmaf(w2.w,h.w,acc[2][b]))));
                    acc[3][b] = fmaf(w3.x,h.x,fmaf(w3.y,h.y,fmaf(w3.z,h.z,fmaf(w3.w,h.w,acc[3][b]))));
                }
            }
            __syncthreads();            // done reading hstage; U becomes red[]
            #pragma unroll
            for (int r = 0; r < 4; ++r)
                #pragma unroll
                for (int b = 0; b < 8; ++b)
                    lds[O_U + ((wv * 4 + r) * 8 + b) * 68 + ks] = acc[r][b];
        }
        __syncthreads();
        {   // K-reduce + bias + x-part
            int o = tid >> 1, hf = tid & 1;
            const float* rr = &lds[O_U + o * 68 + hf * 32];
            float s = 0.0f;
            #pragma unroll
            for (int c = 0; c < 8; ++c) { float4 v = *(const float4*)&rr[c * 4]; s += v.x + v.y + v.z + v.w; }
            s += __shfl_xor(s, 1);
            if (hf == 0) {
                int r = o >> 3, b = o & 7;
                lds[O_GAT + o] = s + lds[O_B1 + r]
                               + lds[O_WX + r * 2]     * lds[O_XS + b * 2]
                               + lds[O_WX + r * 2 + 1] * lds[O_XS + b * 2 + 1];
            }
        }
        __syncthreads();
        if (tid < 32) {     // activations + cell update + publish h1 (IC atomic)
            int jj = tid >> 3, b = tid & 7;
            float gi = sigm(lds[O_GAT + (0 * 4 + jj) * 8 + b]);
            float gf = sigm(lds[O_GAT + (1 * 4 + jj) * 8 + b]);
            float gg = tanh_fast(lds[O_GAT + (2 * 4 + jj) * 8 + b]);
            float go = sigm(lds[O_GAT + (3 * 4 + jj) * 8 + b]);
            float c  = gf * lds[O_C1 + tid] + gi * gg;
            lds[O_C1 + tid] = c;
            __hip_atomic_store(&h1g[p * 8192 + (bh * 8 + b) * 512 + j0 + jj],
                               go * tanh_fast(c), __ATOMIC_RELAXED, AGT);
        }
        gbar(flags, wg, tid, ++ph);   // THE one barrier per step: h1_t broadcast

        // ================= phase B : layer 2 (no barrier after) =================
        // out duty: y_{t-1} from outred[pq] (written in B(t-1); bar_t between).
        if (wg < 16 && t > 0 && tid < 64) {
            const unsigned long long* row64 =
                (const unsigned long long*)(outred + pq * 2048 + wg * 128);
            U64F2 v; v.u = __hip_atomic_load(&row64[tid], __ATOMIC_RELAXED, AGT);
            float s = v.f[0] + v.f[1];
            #pragma unroll
            for (int off = 32; off >= 1; off >>= 1) s += __shfl_xor(s, off);
            if (tid == 0) out[wg * T + (t - 1)] = s + bo;
        }
        {   // stage [h1(t) | h2(t-1)]; BATCHED: 16 IC loads in flight, then LDS writes
            const unsigned long long* h1s = (const unsigned long long*)(h1g + p  * 8192);
            const unsigned long long* h2s = (const unsigned long long*)(h2g + pq * 8192);
            unsigned long long tmp[16];
            #pragma unroll
            for (int i = 0; i < 16; ++i) {
                int idx = tid + i * NTHR;
                int b = idx >> 9, pos = idx & 511;      // u64 units, 512 per [h1|h2] row
                if (pos < 256)
                    tmp[i] = __hip_atomic_load(&h1s[(bh * 8 + b) * 256 + pos], __ATOMIC_RELAXED, AGT);
                else if (t == 0)
                    tmp[i] = 0ull;
                else
                    tmp[i] = __hip_atomic_load(&h2s[(bh * 8 + b) * 256 + (pos - 256)], __ATOMIC_RELAXED, AGT);
            }
            #pragma unroll
            for (int i = 0; i < 16; ++i) {
                int idx = tid + i * NTHR;
                int b = idx >> 9, pos = idx & 511;
                *(unsigned long long*)&lds[O_U + b * 1024 + pos * 2] = tmp[i];
            }
        }
        __syncthreads();
        {
            float acc[4][8];
            #pragma unroll
            for (int r = 0; r < 4; ++r)
                #pragma unroll
                for (int b = 0; b < 8; ++b) acc[r][b] = 0.0f;
            const float* Wb = &lds[O_W2 + wv * 4 * 1024];
            #pragma unroll
            for (int c = 0; c < 4; ++c) {
                int k = ks * 4 + c * 256;
                float4 w0 = *(const float4*)&Wb[0 * 1024 + k];
                float4 w1 = *(const float4*)&Wb[1 * 1024 + k];
                float4 w2 = *(const float4*)&Wb[2 * 1024 + k];
                float4 w3 = *(const float4*)&Wb[3 * 1024 + k];
                #pragma unroll
                for (int b = 0; b < 8; ++b) {
                    float4 h = *(const float4*)&lds[O_U + b * 1024 + k];
                    acc[0][b] = fmaf(w0.x,h.x,fmaf(w0.y,h.y,fmaf(w0.z,h.z,fmaf(w0.w,h.w,acc[0][b]))));
                    acc[1][b] = fmaf(w1.x,h.x,fmaf(w1.y,h.y,fmaf(w1.z,h.z,fmaf(w1.w,h.w,acc[1][b]))));
                    acc[2][b] = fmaf(w2.x,h.x,fmaf(w2.y,h.y,fmaf(w2.z,h.z,fmaf(w2.w,h.w,acc[2][b]))));
                    acc[3][b] = fmaf(w3.x,h.x,fmaf(w3.y,h.y,fmaf(w3.z,h.z,fmaf(w3.w,h.w,acc[3][b]))));
                }
            }
            __syncthreads();
            #pragma unroll
            for (int r = 0; r < 4; ++r)
                #pragma unroll
                for (int b = 0; b < 8; ++b)
                    lds[O_U + ((wv * 4 + r) * 8 + b) * 68 + ks] = acc[r][b];
        }
        __syncthreads();
        {
            int o = tid >> 1, hf = tid & 1;
            const float* rr = &lds[O_U + o * 68 + hf * 32];
            float s = 0.0f;
            #pragma unroll
            for (int c = 0; c < 8; ++c) { float4 v = *(const float4*)&rr[c * 4]; s += v.x + v.y + v.z + v.w; }
            s += __shfl_xor(s, 1);
            if (hf == 0) {
                int r = o >> 3;
                lds[O_GAT + o] = s + lds[O_B2 + r];
            }
        }
        __syncthreads();
        if (tid < 32) {
            int jj = tid >> 3, b = tid & 7;
            float gi = sigm(lds[O_GAT + (0 * 4 + jj) * 8 + b]);
            float gf = sigm(lds[O_GAT + (1 * 4 + jj) * 8 + b]);
            float gg = tanh_fast(lds[O_GAT + (2 * 4 + jj) * 8 + b]);
            float go = sigm(lds[O_GAT + (3 * 4 + jj) * 8 + b]);
            float c  = gf * lds[O_C2 + tid] + gi * gg;
            lds[O_C2 + tid] = c;
            float h = go * tanh_fast(c);
            __hip_atomic_store(&h2g[p * 8192 + (bh * 8 + b) * 512 + j0 + jj],
                               h, __ATOMIC_RELAXED, AGT);
            lds[O_HN + tid] = lds[O_WO + jj] * h;      // product for W_out dot
        }
        __syncthreads();
        if (tid < 8) {      // per-batch partial of W_out dot for this j-group
            float pr = lds[O_HN + tid] + lds[O_HN + 8 + tid] + lds[O_HN + 16 + tid] + lds[O_HN + 24 + tid];
            __hip_atomic_store(&outred[p * 2048 + (bh * 8 + tid) * 128 + jg],
                               pr, __ATOMIC_RELAXED, AGT);
        }
        // no barrier here — next A-barrier (bar_{t+1}) covers B(t)'s publishes
    }

    // final barrier so the tail sees every WG's B(T-1) outred writes
    gbar(flags, wg, tid, ++ph);

    // tail: output for t = T-1
    if (wg < 16 && tid < 64) {
        const unsigned long long* row64 =
            (const unsigned long long*)(outred + ((T - 1) & 1) * 2048 + wg * 128);
        U64F2 v; v.u = __hip_atomic_load(&row64[tid], __ATOMIC_RELAXED, AGT);
        float s = v.f[0] + v.f[1];
        #pragma unroll
        for (int off = 32; off >= 1; off >>= 1) s += __shfl_xor(s, off);
        if (tid == 0) out[wg * T + (T - 1)] = s + bo;
    }
}

extern "C" void kernel_launch(void* const* d_in, const int* in_sizes, int n_in,
                              void* d_out, int out_size, void* d_ws, size_t ws_size,
                              hipStream_t stream) {
    const float* xin  = (const float*)d_in[0];
    const float* Wih1 = (const float*)d_in[1];
    const float* Whh1 = (const float*)d_in[2];
    const float* bih1 = (const float*)d_in[3];
    const float* bhh1 = (const float*)d_in[4];
    const float* Wih2 = (const float*)d_in[5];
    const float* Whh2 = (const float*)d_in[6];
    const float* bih2 = (const float*)d_in[7];
    const float* bhh2 = (const float*)d_in[8];
    const float* Wout = (const float*)d_in[9];
    const float* bout = (const float*)d_in[10];
    float* outp = (float*)d_out;
    int T = in_sizes[0] / 32;           // input is [16][T][2]

    unsigned* flags = (unsigned*)d_ws;                  // 256 packed u32 (region zeroed)
    float* h1g    = (float*)d_ws + 4096;                // [2][16][512]
    float* h2g    = h1g + 16384;                        // [2][16][512]
    float* outredp= h2g + 16384;                        // [2][16][128]

    hipLaunchKernelGGL(ws_init_kernel, dim3(1), dim3(256), 0, stream, flags);

    void* args[] = { &xin, &Wih1, &Whh1, &bih1, &bhh1, &Wih2, &Whh2, &bih2, &bhh2,
                     &Wout, &bout, &outp, &flags, &h1g, &h2g, &outredp, &T };
    hipLaunchCooperativeKernel((void*)lstm_kernel, dim3(NWG), dim3(NTHR), args, 0, stream);
}